// Round 2
// baseline (1078.622 us; speedup 1.0000x reference)
//
#include <hip/hip_runtime.h>
#include <hip/hip_bf16.h>
#include <math.h>

#define B_   16
#define C_   16
#define S_   64
#define HW_  4096
#define T_   50
#define K_   26
#define F_   416   // C_*K_
#define HID_ 256
#define NC_  7
#define DT_  0.5f
#define BCHW_ (B_*C_*HW_)
#define M_   (B_*HW_)   // 65536 rows into the MLP

__device__ __forceinline__ float fast_tanh(float x){
    float ax = fabsf(x);
    float e  = __expf(2.f*ax);          // v_exp_f32; inf for large x -> r=1
    float r  = 1.f - 2.f/(e + 1.f);
    return copysignf(r, x);
}

// ---------------------------------------------------------------------------
// 3x3 conv, zero 'SAME' padding. grid = B*Cout = 256 blocks, 256 threads.
// ACT: 0 = relu, 1 = tanh
// ---------------------------------------------------------------------------
template<int CIN, int ACT>
__global__ __launch_bounds__(256) void conv3x3_kernel(
    const float* __restrict__ in, const float* __restrict__ w,
    const float* __restrict__ bias, float* __restrict__ out)
{
    __shared__ float plane[HW_];
    const int blk = blockIdx.x;
    const int b  = blk >> 4;
    const int co = blk & 15;
    const int tid = threadIdx.x;

    float acc[16];
    const float bv = bias[co];
    #pragma unroll
    for (int i = 0; i < 16; i++) acc[i] = bv;

    for (int ci = 0; ci < CIN; ci++){
        const float* src = in + (size_t)(b*CIN + ci)*HW_;
        #pragma unroll
        for (int i = 0; i < 16; i++) plane[tid + i*256] = src[tid + i*256];
        __syncthreads();

        float wv[9];
        const float* wp = w + (size_t)(co*CIN + ci)*9;
        #pragma unroll
        for (int j = 0; j < 9; j++) wv[j] = wp[j];

        #pragma unroll
        for (int i = 0; i < 16; i++){
            int px = tid + i*256;
            int y = px >> 6, x = px & 63;
            float s = 0.f;
            #pragma unroll
            for (int dy = 0; dy < 3; dy++){
                int yy = y + dy - 1;
                bool yok = ((unsigned)yy < 64u);
                #pragma unroll
                for (int dx = 0; dx < 3; dx++){
                    int xx = x + dx - 1;
                    bool ok = yok && ((unsigned)xx < 64u);
                    int idx = ((yy & 63) << 6) | (xx & 63);   // always in-bounds
                    float v = ok ? plane[idx] : 0.f;
                    s = fmaf(wv[dy*3+dx], v, s);
                }
            }
            acc[i] += s;
        }
        __syncthreads();
    }

    float* dst = out + (size_t)(b*C_ + co)*HW_;
    #pragma unroll
    for (int i = 0; i < 16; i++){
        float v = acc[i];
        v = (ACT == 0) ? fmaxf(v, 0.f) : fast_tanh(v);
        dst[tid + i*256] = v;
    }
}

// ---------------------------------------------------------------------------
// 50-step coRNN ODE. wy is block-diagonal (per-channel circular 3x3 stencil),
// so each (b,c) 64x64 field is independent -> one workgroup per field.
// hy double-buffered in LDS; hz/omega/alpha in registers. Output yseq bf16,
// layout [t][bc][hw].
// ---------------------------------------------------------------------------
__global__ __launch_bounds__(256) void ode_kernel(
    const float* __restrict__ omega, const float* __restrict__ alpha,
    const float* __restrict__ hy0,   const float* __restrict__ wy,
    __hip_bfloat16* __restrict__ yseq)
{
    __shared__ float hyb[2][HW_];
    const int blk = blockIdx.x;            // b*16 + c
    const int c   = blk & 15;
    const int tid = threadIdx.x;
    const size_t off = (size_t)blk * HW_;

    float om[16], al[16], hz[16];
    #pragma unroll
    for (int i = 0; i < 16; i++){
        int px = tid + i*256;
        om[i] = omega[off + px];
        al[i] = alpha[off + px];
        hz[i] = 0.f;
        hyb[0][px] = hy0[off + px];
    }
    float wv[9];
    const float* wp = wy + (size_t)(c*C_ + c)*9;
    #pragma unroll
    for (int j = 0; j < 9; j++) wv[j] = wp[j];
    __syncthreads();

    int cur = 0;
    for (int t = 0; t < T_; t++){
        __hip_bfloat16* yout = yseq + (size_t)t*BCHW_ + off;
        const float* hp = hyb[cur];
        float* hn = hyb[cur ^ 1];
        #pragma unroll
        for (int i = 0; i < 16; i++){
            int px = tid + i*256;
            int y = px >> 6, x = px & 63;
            int ym = (y + 63) & 63, yp = (y + 1) & 63;
            int xm = (x + 63) & 63, xp = (x + 1) & 63;
            float s = wv[0]*hp[(ym<<6)|xm] + wv[1]*hp[(ym<<6)|x] + wv[2]*hp[(ym<<6)|xp]
                    + wv[3]*hp[(y <<6)|xm] + wv[4]*hp[(y <<6)|x] + wv[5]*hp[(y <<6)|xp]
                    + wv[6]*hp[(yp<<6)|xm] + wv[7]*hp[(yp<<6)|x] + wv[8]*hp[(yp<<6)|xp];
            float sf  = fast_tanh(s);
            float hyv = hp[(y<<6)|x];
            float nz  = hz[i] + DT_*(sf - om[i]*hyv - al[i]*hz[i]);
            float ny  = hyv + DT_*nz;
            hz[i] = nz;
            hn[px] = ny;
            yout[px] = __float2bfloat16(ny);
        }
        __syncthreads();
        cur ^= 1;
    }
}

// ---------------------------------------------------------------------------
// rfft magnitude via Goertzel. One thread per (b,c,hw) row; 50 samples in
// registers; 26 bins. Writes TRANSPOSED feature matrix:
//   fT[(c*26+k)*M_ + b*HW + hw]   (bf16, hw-coalesced)
// ---------------------------------------------------------------------------
__global__ __launch_bounds__(256) void dft_kernel(
    const __hip_bfloat16* __restrict__ yseq, __hip_bfloat16* __restrict__ fT)
{
    __shared__ float ctab[K_];
    const int tid = threadIdx.x;
    if (tid < K_) ctab[tid] = cosf(6.283185307179586f * (float)tid / (float)T_);
    __syncthreads();

    const int blk = blockIdx.x;            // 4096 blocks
    const int bc  = blk >> 4;              // 0..255
    const int hw  = ((blk & 15) << 8) | tid;
    const int b = bc >> 4, c = bc & 15;

    float y[T_];
    const __hip_bfloat16* src = yseq + (size_t)bc*HW_ + hw;
    #pragma unroll
    for (int t = 0; t < T_; t++) y[t] = __bfloat162float(src[(size_t)t * BCHW_]);

    const int row = b*HW_ + hw;
    for (int k = 0; k < K_; k++){
        float c1 = ctab[k];
        float tc = 2.f*c1;
        float s1 = 0.f, s2 = 0.f;
        #pragma unroll
        for (int t = 0; t < T_; t++){
            float s0 = fmaf(tc, s1, y[t] - s2);
            s2 = s1; s1 = s0;
        }
        float p = fmaf(s1, s1, fmaf(s2, s2, -tc*s1*s2));
        fT[(size_t)(c*K_ + k)*M_ + row] = __float2bfloat16(sqrtf(fmaxf(p, 0.f)));
    }
}

// ---------------------------------------------------------------------------
// GEMM layer 1: C = relu(A @ B + bias), A given TRANSPOSED in bf16:
// AT[K][M]. 128x128 tile, 8x8 per thread, BK=16.
// ---------------------------------------------------------------------------
__global__ __launch_bounds__(256) void gemm_bf16AT_kernel(
    const __hip_bfloat16* __restrict__ AT, const float* __restrict__ Bw,
    const float* __restrict__ bias, float* __restrict__ Cout,
    int M, int N, int Kd)
{
    __shared__ float As[16][132];   // [k][m]
    __shared__ float Bs[16][132];   // [k][n]
    const int tid = threadIdx.x;
    const int tx = tid & 15, ty = tid >> 4;
    const int m0 = blockIdx.x * 128;
    const int n0 = blockIdx.y * 128;

    float acc[8][8];
    #pragma unroll
    for (int i = 0; i < 8; i++)
        #pragma unroll
        for (int j = 0; j < 8; j++) acc[i][j] = 0.f;

    const int ak = tid >> 4;          // 0..15 (k within tile)
    const int am = (tid & 15) * 8;    // 0..120 (m within tile)
    const int bk = tid >> 4, bnq = (tid & 15) * 8;

    for (int k0 = 0; k0 < Kd; k0 += 16){
        const __hip_bfloat16* ap = AT + (size_t)(k0 + ak)*M + m0 + am;
        float4 raw = *(const float4*)ap;   // 8 bf16
        unsigned int u0 = __float_as_uint(raw.x);
        unsigned int u1 = __float_as_uint(raw.y);
        unsigned int u2 = __float_as_uint(raw.z);
        unsigned int u3 = __float_as_uint(raw.w);
        As[ak][am+0] = __uint_as_float(u0 << 16);
        As[ak][am+1] = __uint_as_float(u0 & 0xffff0000u);
        As[ak][am+2] = __uint_as_float(u1 << 16);
        As[ak][am+3] = __uint_as_float(u1 & 0xffff0000u);
        As[ak][am+4] = __uint_as_float(u2 << 16);
        As[ak][am+5] = __uint_as_float(u2 & 0xffff0000u);
        As[ak][am+6] = __uint_as_float(u3 << 16);
        As[ak][am+7] = __uint_as_float(u3 & 0xffff0000u);

        const float* bp = Bw + (size_t)(k0 + bk)*N + n0 + bnq;
        float4 b0 = *(const float4*)bp;
        float4 b1 = *(const float4*)(bp + 4);
        *(float4*)&Bs[bk][bnq]     = b0;
        *(float4*)&Bs[bk][bnq + 4] = b1;
        __syncthreads();

        #pragma unroll
        for (int kk = 0; kk < 16; kk++){
            float4 av0 = *(const float4*)&As[kk][ty*8];
            float4 av1 = *(const float4*)&As[kk][ty*8 + 4];
            float4 bv0 = *(const float4*)&Bs[kk][tx*8];
            float4 bv1 = *(const float4*)&Bs[kk][tx*8 + 4];
            float av[8] = {av0.x,av0.y,av0.z,av0.w,av1.x,av1.y,av1.z,av1.w};
            float bv[8] = {bv0.x,bv0.y,bv0.z,bv0.w,bv1.x,bv1.y,bv1.z,bv1.w};
            #pragma unroll
            for (int i = 0; i < 8; i++)
                #pragma unroll
                for (int j = 0; j < 8; j++)
                    acc[i][j] = fmaf(av[i], bv[j], acc[i][j]);
        }
        __syncthreads();
    }

    float bvals[8];
    #pragma unroll
    for (int j = 0; j < 8; j++) bvals[j] = bias[n0 + tx*8 + j];
    #pragma unroll
    for (int i = 0; i < 8; i++){
        int row = m0 + ty*8 + i;
        float o[8];
        #pragma unroll
        for (int j = 0; j < 8; j++)
            o[j] = fmaxf(acc[i][j] + bvals[j], 0.f);
        float* cp = Cout + (size_t)row*N + n0 + tx*8;
        *(float4*)cp       = make_float4(o[0],o[1],o[2],o[3]);
        *(float4*)(cp + 4) = make_float4(o[4],o[5],o[6],o[7]);
    }
}

// ---------------------------------------------------------------------------
// fp32 GEMM (layers 2,3): C = relu(A(MxK) @ B(KxN) + bias). 128x128 tile,
// 8x8 per thread, BK=16.
// ---------------------------------------------------------------------------
__global__ __launch_bounds__(256) void gemm_kernel(
    const float* __restrict__ A, const float* __restrict__ Bw,
    const float* __restrict__ bias, float* __restrict__ Cout,
    int M, int N, int Kd)
{
    __shared__ float As[16][132];
    __shared__ float Bs[16][132];
    const int tid = threadIdx.x;
    const int tx = tid & 15, ty = tid >> 4;
    const int m0 = blockIdx.x * 128;
    const int n0 = blockIdx.y * 128;

    float acc[8][8];
    #pragma unroll
    for (int i = 0; i < 8; i++)
        #pragma unroll
        for (int j = 0; j < 8; j++) acc[i][j] = 0.f;

    const int arow = tid >> 1, akq = (tid & 1) * 8;
    const int bk   = tid >> 4, bnq = (tid & 15) * 8;

    for (int k0 = 0; k0 < Kd; k0 += 16){
        const float* ap = A + (size_t)(m0 + arow)*Kd + k0 + akq;
        float4 a0 = *(const float4*)ap;
        float4 a1 = *(const float4*)(ap + 4);
        As[akq+0][arow] = a0.x; As[akq+1][arow] = a0.y;
        As[akq+2][arow] = a0.z; As[akq+3][arow] = a0.w;
        As[akq+4][arow] = a1.x; As[akq+5][arow] = a1.y;
        As[akq+6][arow] = a1.z; As[akq+7][arow] = a1.w;

        const float* bp = Bw + (size_t)(k0 + bk)*N + n0 + bnq;
        float4 b0 = *(const float4*)bp;
        float4 b1 = *(const float4*)(bp + 4);
        *(float4*)&Bs[bk][bnq]     = b0;
        *(float4*)&Bs[bk][bnq + 4] = b1;
        __syncthreads();

        #pragma unroll
        for (int kk = 0; kk < 16; kk++){
            float4 av0 = *(const float4*)&As[kk][ty*8];
            float4 av1 = *(const float4*)&As[kk][ty*8 + 4];
            float4 bv0 = *(const float4*)&Bs[kk][tx*8];
            float4 bv1 = *(const float4*)&Bs[kk][tx*8 + 4];
            float av[8] = {av0.x,av0.y,av0.z,av0.w,av1.x,av1.y,av1.z,av1.w};
            float bv[8] = {bv0.x,bv0.y,bv0.z,bv0.w,bv1.x,bv1.y,bv1.z,bv1.w};
            #pragma unroll
            for (int i = 0; i < 8; i++)
                #pragma unroll
                for (int j = 0; j < 8; j++)
                    acc[i][j] = fmaf(av[i], bv[j], acc[i][j]);
        }
        __syncthreads();
    }

    float bvals[8];
    #pragma unroll
    for (int j = 0; j < 8; j++) bvals[j] = bias[n0 + tx*8 + j];
    #pragma unroll
    for (int i = 0; i < 8; i++){
        int row = m0 + ty*8 + i;
        float o[8];
        #pragma unroll
        for (int j = 0; j < 8; j++)
            o[j] = fmaxf(acc[i][j] + bvals[j], 0.f);
        float* cp = Cout + (size_t)row*N + n0 + tx*8;
        *(float4*)cp       = make_float4(o[0],o[1],o[2],o[3]);
        *(float4*)(cp + 4) = make_float4(o[4],o[5],o[6],o[7]);
    }
}

// ---------------------------------------------------------------------------
// Final layer 256->7 fused with (BHW,7)->(B,7,H,W) transpose.
// ---------------------------------------------------------------------------
__global__ __launch_bounds__(256) void final_kernel(
    const float* __restrict__ h, const float* __restrict__ w,
    const float* __restrict__ bias, float* __restrict__ out)
{
    __shared__ float ws[HID_*NC_];
    __shared__ float bs[NC_];
    const int tid = threadIdx.x;
    for (int i = tid; i < HID_*NC_; i += 256) ws[i] = w[i];
    if (tid < NC_) bs[tid] = bias[tid];
    __syncthreads();

    const int row = blockIdx.x*256 + tid;   // 0..65535
    const float* hp = h + (size_t)row*HID_;
    float acc[NC_];
    #pragma unroll
    for (int j = 0; j < NC_; j++) acc[j] = bs[j];

    for (int k = 0; k < HID_; k += 4){
        float4 v = *(const float4*)(hp + k);
        #pragma unroll
        for (int j = 0; j < NC_; j++){
            acc[j] = fmaf(v.x, ws[(k+0)*NC_ + j], acc[j]);
            acc[j] = fmaf(v.y, ws[(k+1)*NC_ + j], acc[j]);
            acc[j] = fmaf(v.z, ws[(k+2)*NC_ + j], acc[j]);
            acc[j] = fmaf(v.w, ws[(k+3)*NC_ + j], acc[j]);
        }
    }
    const int b = row >> 12, hw = row & 4095;
    #pragma unroll
    for (int j = 0; j < NC_; j++)
        out[(size_t)(b*NC_ + j)*HW_ + hw] = acc[j];
}

// ---------------------------------------------------------------------------
// Workspace plan (peak 159,383,552 bytes ~ 152 MiB):
//   [0        , 104857600)  yseq  bf16 [t][bc][hw]           (phases: ODE w, DFT r)
//   [104857600, 159383552)  fbufT bf16 [416][65536]          (DFT w, GEMM1 r)
//     aliased inside fbufT region (dead before DFT):
//       tmp1 @ +0MB, tmp2 @ +4MB, omega @ +8MB, alpha @ +12MB, hy0 @ +16MB
//   h1 (fp32 64MB) @ 0         -- GEMM1 out (yseq dead)
//   h2 (fp32 64MB) @ 67108864  -- GEMM2 out (fbufT dead)
//   h3 (fp32 64MB) @ 0         -- GEMM3 out (h1 dead)
// ---------------------------------------------------------------------------
extern "C" void kernel_launch(void* const* d_in, const int* in_sizes, int n_in,
                              void* d_out, int out_size, void* d_ws, size_t ws_size,
                              hipStream_t stream)
{
    const float* x     = (const float*)d_in[0];
    const float* om_w1 = (const float*)d_in[1];  const float* om_b1 = (const float*)d_in[2];
    const float* om_w2 = (const float*)d_in[3];  const float* om_b2 = (const float*)d_in[4];
    const float* om_w3 = (const float*)d_in[5];  const float* om_b3 = (const float*)d_in[6];
    const float* al_w1 = (const float*)d_in[7];  const float* al_b1 = (const float*)d_in[8];
    const float* al_w2 = (const float*)d_in[9];  const float* al_b2 = (const float*)d_in[10];
    const float* al_w3 = (const float*)d_in[11]; const float* al_b3 = (const float*)d_in[12];
    const float* hy_w1 = (const float*)d_in[13]; const float* hy_b1 = (const float*)d_in[14];
    const float* hy_w2 = (const float*)d_in[15]; const float* hy_b2 = (const float*)d_in[16];
    const float* hy_w3 = (const float*)d_in[17]; const float* hy_b3 = (const float*)d_in[18];
    const float* hy_w4 = (const float*)d_in[19]; const float* hy_b4 = (const float*)d_in[20];
    const float* wy    = (const float*)d_in[21];
    const float* ro_w1 = (const float*)d_in[22]; const float* ro_b1 = (const float*)d_in[23];
    const float* ro_w2 = (const float*)d_in[24]; const float* ro_b2 = (const float*)d_in[25];
    const float* ro_w3 = (const float*)d_in[26]; const float* ro_b3 = (const float*)d_in[27];
    const float* ro_w4 = (const float*)d_in[28]; const float* ro_b4 = (const float*)d_in[29];
    float* out = (float*)d_out;

    char* wsb = (char*)d_ws;
    const size_t YSEQ_BYTES = (size_t)T_ * BCHW_ * 2;          // 104,857,600
    __hip_bfloat16* yseq  = (__hip_bfloat16*)wsb;
    __hip_bfloat16* fbufT = (__hip_bfloat16*)(wsb + YSEQ_BYTES);

    const size_t MB4 = (size_t)BCHW_ * 4;                      // 4 MiB per plane set
    float* tmp1  = (float*)(wsb + YSEQ_BYTES + 0*MB4);
    float* tmp2  = (float*)(wsb + YSEQ_BYTES + 1*MB4);
    float* omega = (float*)(wsb + YSEQ_BYTES + 2*MB4);
    float* alpha = (float*)(wsb + YSEQ_BYTES + 3*MB4);
    float* hy0   = (float*)(wsb + YSEQ_BYTES + 4*MB4);

    float* h1 = (float*)(wsb + 0);
    float* h2 = (float*)(wsb + (size_t)M_ * HID_ * 4);         // @ 64 MiB
    float* h3 = (float*)(wsb + 0);

    dim3 blk(256);
    // omega encoder
    conv3x3_kernel<1,0> <<<256, blk, 0, stream>>>(x,    om_w1, om_b1, tmp1);
    conv3x3_kernel<16,0><<<256, blk, 0, stream>>>(tmp1, om_w2, om_b2, tmp2);
    conv3x3_kernel<16,0><<<256, blk, 0, stream>>>(tmp2, om_w3, om_b3, omega);
    // alpha encoder
    conv3x3_kernel<1,0> <<<256, blk, 0, stream>>>(x,    al_w1, al_b1, tmp1);
    conv3x3_kernel<16,0><<<256, blk, 0, stream>>>(tmp1, al_w2, al_b2, tmp2);
    conv3x3_kernel<16,0><<<256, blk, 0, stream>>>(tmp2, al_w3, al_b3, alpha);
    // hy encoder
    conv3x3_kernel<1,0> <<<256, blk, 0, stream>>>(x,    hy_w1, hy_b1, tmp1);
    conv3x3_kernel<16,0><<<256, blk, 0, stream>>>(tmp1, hy_w2, hy_b2, tmp2);
    conv3x3_kernel<16,0><<<256, blk, 0, stream>>>(tmp2, hy_w3, hy_b3, tmp1);
    conv3x3_kernel<16,1><<<256, blk, 0, stream>>>(tmp1, hy_w4, hy_b4, hy0);
    // 50-step ODE (single launch), bf16 output
    ode_kernel<<<256, blk, 0, stream>>>(omega, alpha, hy0, wy, yseq);
    // rfft magnitude -> transposed bf16 feature matrix
    dft_kernel<<<4096, blk, 0, stream>>>(yseq, fbufT);
    // readout MLP
    gemm_bf16AT_kernel<<<dim3(512,2), blk, 0, stream>>>(fbufT, ro_w1, ro_b1, h1, M_, HID_, F_);
    gemm_kernel<<<dim3(512,2), blk, 0, stream>>>(h1, ro_w2, ro_b2, h2, M_, HID_, HID_);
    gemm_kernel<<<dim3(512,2), blk, 0, stream>>>(h2, ro_w3, ro_b3, h3, M_, HID_, HID_);
    final_kernel<<<256, blk, 0, stream>>>(h3, ro_w4, ro_b4, out);
}

// Round 3
// 823.970 us; speedup vs baseline: 1.3091x; 1.3091x over previous
//
#include <hip/hip_runtime.h>
#include <hip/hip_bf16.h>
#include <math.h>

#define B_   16
#define C_   16
#define S_   64
#define HW_  4096
#define T_   50
#define K_   26
#define F_   416   // C_*K_
#define HID_ 256
#define NC_  7
#define DT_  0.5f
#define BCHW_ (B_*C_*HW_)
#define M_   (B_*HW_)   // 65536 rows into the MLP

typedef short bf16x8 __attribute__((ext_vector_type(8)));
typedef float f32x4  __attribute__((ext_vector_type(4)));

__device__ __forceinline__ void gld_lds16(const void* g, void* l){
    __builtin_amdgcn_global_load_lds(
        (const __attribute__((address_space(1))) void*)g,
        (__attribute__((address_space(3))) void*)l, 16, 0, 0);
}

__device__ __forceinline__ float fast_tanh(float x){
    float ax = fabsf(x);
    float e  = __expf(2.f*ax);
    float r  = 1.f - 2.f/(e + 1.f);
    return copysignf(r, x);
}

// ---------------------------------------------------------------------------
// 3x3 conv, zero 'SAME' padding. grid = B*Cout = 256 blocks, 256 threads.
// ---------------------------------------------------------------------------
template<int CIN, int ACT>
__global__ __launch_bounds__(256) void conv3x3_kernel(
    const float* __restrict__ in, const float* __restrict__ w,
    const float* __restrict__ bias, float* __restrict__ out)
{
    __shared__ float plane[HW_];
    const int blk = blockIdx.x;
    const int b  = blk >> 4;
    const int co = blk & 15;
    const int tid = threadIdx.x;

    float acc[16];
    const float bv = bias[co];
    #pragma unroll
    for (int i = 0; i < 16; i++) acc[i] = bv;

    for (int ci = 0; ci < CIN; ci++){
        const float* src = in + (size_t)(b*CIN + ci)*HW_;
        #pragma unroll
        for (int i = 0; i < 16; i++) plane[tid + i*256] = src[tid + i*256];
        __syncthreads();

        float wv[9];
        const float* wp = w + (size_t)(co*CIN + ci)*9;
        #pragma unroll
        for (int j = 0; j < 9; j++) wv[j] = wp[j];

        #pragma unroll
        for (int i = 0; i < 16; i++){
            int px = tid + i*256;
            int y = px >> 6, x = px & 63;
            float s = 0.f;
            #pragma unroll
            for (int dy = 0; dy < 3; dy++){
                int yy = y + dy - 1;
                bool yok = ((unsigned)yy < 64u);
                #pragma unroll
                for (int dx = 0; dx < 3; dx++){
                    int xx = x + dx - 1;
                    bool ok = yok && ((unsigned)xx < 64u);
                    int idx = ((yy & 63) << 6) | (xx & 63);
                    float v = ok ? plane[idx] : 0.f;
                    s = fmaf(wv[dy*3+dx], v, s);
                }
            }
            acc[i] += s;
        }
        __syncthreads();
    }

    float* dst = out + (size_t)(b*C_ + co)*HW_;
    #pragma unroll
    for (int i = 0; i < 16; i++){
        float v = acc[i];
        v = (ACT == 0) ? fmaxf(v, 0.f) : fast_tanh(v);
        dst[tid + i*256] = v;
    }
}

// ---------------------------------------------------------------------------
// 50-step coRNN ODE. One workgroup per (b,c) 64x64 field; hy double-buffered
// in LDS; hz/omega/alpha in registers. Output yseq bf16 [t][bc][hw].
// ---------------------------------------------------------------------------
__global__ __launch_bounds__(256) void ode_kernel(
    const float* __restrict__ omega, const float* __restrict__ alpha,
    const float* __restrict__ hy0,   const float* __restrict__ wy,
    __hip_bfloat16* __restrict__ yseq)
{
    __shared__ float hyb[2][HW_];
    const int blk = blockIdx.x;            // b*16 + c
    const int c   = blk & 15;
    const int tid = threadIdx.x;
    const size_t off = (size_t)blk * HW_;

    float om[16], al[16], hz[16];
    #pragma unroll
    for (int i = 0; i < 16; i++){
        int px = tid + i*256;
        om[i] = omega[off + px];
        al[i] = alpha[off + px];
        hz[i] = 0.f;
        hyb[0][px] = hy0[off + px];
    }
    float wv[9];
    const float* wp = wy + (size_t)(c*C_ + c)*9;
    #pragma unroll
    for (int j = 0; j < 9; j++) wv[j] = wp[j];
    __syncthreads();

    int cur = 0;
    for (int t = 0; t < T_; t++){
        __hip_bfloat16* yout = yseq + (size_t)t*BCHW_ + off;
        const float* hp = hyb[cur];
        float* hn = hyb[cur ^ 1];
        #pragma unroll
        for (int i = 0; i < 16; i++){
            int px = tid + i*256;
            int y = px >> 6, x = px & 63;
            int ym = (y + 63) & 63, yp = (y + 1) & 63;
            int xm = (x + 63) & 63, xp = (x + 1) & 63;
            float s = wv[0]*hp[(ym<<6)|xm] + wv[1]*hp[(ym<<6)|x] + wv[2]*hp[(ym<<6)|xp]
                    + wv[3]*hp[(y <<6)|xm] + wv[4]*hp[(y <<6)|x] + wv[5]*hp[(y <<6)|xp]
                    + wv[6]*hp[(yp<<6)|xm] + wv[7]*hp[(yp<<6)|x] + wv[8]*hp[(yp<<6)|xp];
            float sf  = fast_tanh(s);
            float hyv = hp[(y<<6)|x];
            float nz  = hz[i] + DT_*(sf - om[i]*hyv - al[i]*hz[i]);
            float ny  = hyv + DT_*nz;
            hz[i] = nz;
            hn[px] = ny;
            yout[px] = __float2bfloat16(ny);
        }
        __syncthreads();
        cur ^= 1;
    }
}

// ---------------------------------------------------------------------------
// rfft magnitude via Goertzel. One thread per (b,c,hw) row.
// Writes row-major feature matrix: f[(b*HW+hw)*416 + c*26 + k] (bf16).
// ---------------------------------------------------------------------------
__global__ __launch_bounds__(256) void dft_kernel(
    const __hip_bfloat16* __restrict__ yseq, __hip_bfloat16* __restrict__ f)
{
    __shared__ float ctab[K_];
    const int tid = threadIdx.x;
    if (tid < K_) ctab[tid] = cosf(6.283185307179586f * (float)tid / (float)T_);
    __syncthreads();

    const int blk = blockIdx.x;            // 4096 blocks
    const int bc  = blk >> 4;              // 0..255
    const int hw  = ((blk & 15) << 8) | tid;
    const int b = bc >> 4, c = bc & 15;

    float y[T_];
    const __hip_bfloat16* src = yseq + (size_t)bc*HW_ + hw;
    #pragma unroll
    for (int t = 0; t < T_; t++) y[t] = __bfloat162float(src[(size_t)t * BCHW_]);

    __hip_bfloat16* dst = f + (size_t)(b*HW_ + hw)*F_ + c*K_;
    for (int k = 0; k < K_; k++){
        float c1 = ctab[k];
        float tc = 2.f*c1;
        float s1 = 0.f, s2 = 0.f;
        #pragma unroll
        for (int t = 0; t < T_; t++){
            float s0 = fmaf(tc, s1, y[t] - s2);
            s2 = s1; s1 = s0;
        }
        float p = fmaf(s1, s1, fmaf(s2, s2, -tc*s1*s2));
        dst[k] = __float2bfloat16(sqrtf(fmaxf(p, 0.f)));
    }
}

// ---------------------------------------------------------------------------
// Weight prep: w[K][N] fp32 -> wt[N][K] bf16
// ---------------------------------------------------------------------------
__global__ __launch_bounds__(256) void prep_wt_kernel(
    const float* __restrict__ w, __hip_bfloat16* __restrict__ wt, int Kd, int N)
{
    const int n = blockIdx.x;
    for (int k = threadIdx.x; k < Kd; k += 256)
        wt[(size_t)n*Kd + k] = __float2bfloat16(w[(size_t)k*N + n]);
}

// ---------------------------------------------------------------------------
// MFMA GEMM: C = relu(A @ W + bias), bf16 in / fp32 acc / bf16 out.
// A [M][K] bf16, Wt [N][K] bf16 (pre-transposed), C [M][N] bf16.
// 128x128 tile, BK=32, 256 threads = 4 waves, each wave 64x64 (4x4 mfma tiles).
// K, M, N multiples of 32/128/128. m97-style global_load_lds staging.
// ---------------------------------------------------------------------------
__global__ __launch_bounds__(256) void gemm_mfma_kernel(
    const __hip_bfloat16* __restrict__ A, const __hip_bfloat16* __restrict__ Wt,
    const float* __restrict__ bias, __hip_bfloat16* __restrict__ C,
    int M, int N, int Kd)
{
    __shared__ short As[128*32];   // [m][k], 64B rows
    __shared__ short Bs[128*32];   // [n][k]
    const int tid  = threadIdx.x;
    const int lane = tid & 63;
    const int wave = tid >> 6;
    const int wm = (wave & 1) * 64;
    const int wn = (wave >> 1) * 64;
    const int m0 = blockIdx.x * 128;
    const int n0 = blockIdx.y * 128;

    f32x4 acc[4][4];
    #pragma unroll
    for (int i = 0; i < 4; i++)
        #pragma unroll
        for (int j = 0; j < 4; j++)
            acc[i][j] = (f32x4){0.f, 0.f, 0.f, 0.f};

    // staging: thread t covers (row = t>>2, kchunk = t&3) and +64 rows
    const int rloc = tid >> 2;
    const int kc   = (tid & 3) * 8;
    const char* Ag = (const char*)(A  + (size_t)(m0 + rloc)*Kd + kc);
    const char* Bg = (const char*)(Wt + (size_t)(n0 + rloc)*Kd + kc);
    const size_t rstride = (size_t)64 * Kd * 2;   // +64 rows in bytes
    char* AsB = (char*)As + tid*16;
    char* BsB = (char*)Bs + tid*16;

    const int fa = (wm + (lane & 15)) * 32 + (lane >> 4) * 8;  // A frag base (i*16*32 added)
    const int fb = (wn + (lane & 15)) * 32 + (lane >> 4) * 8;

    for (int k0 = 0; k0 < Kd; k0 += 32){
        const char* ag = Ag + (size_t)k0 * 2;
        const char* bg = Bg + (size_t)k0 * 2;
        gld_lds16(ag,           AsB);
        gld_lds16(ag + rstride, AsB + 4096);
        gld_lds16(bg,           BsB);
        gld_lds16(bg + rstride, BsB + 4096);
        __syncthreads();

        bf16x8 af[4], bfv[4];
        #pragma unroll
        for (int i = 0; i < 4; i++){
            af[i]  = *(const bf16x8*)&As[fa + i*16*32];
            bfv[i] = *(const bf16x8*)&Bs[fb + i*16*32];
        }
        #pragma unroll
        for (int i = 0; i < 4; i++)
            #pragma unroll
            for (int j = 0; j < 4; j++)
                acc[i][j] = __builtin_amdgcn_mfma_f32_16x16x32_bf16(
                                af[i], bfv[j], acc[i][j], 0, 0, 0);
        __syncthreads();
    }

    // epilogue: C/D layout col=lane&15, row=(lane>>4)*4+r  [m89-verified]
    const int colb = n0 + wn + (lane & 15);
    const int rowb = m0 + wm + ((lane >> 4) << 2);
    #pragma unroll
    for (int j = 0; j < 4; j++){
        const int col = colb + j*16;
        const float bv = bias[col];
        #pragma unroll
        for (int i = 0; i < 4; i++){
            const int row0 = rowb + i*16;
            #pragma unroll
            for (int r = 0; r < 4; r++){
                float v = acc[i][j][r] + bv;
                v = fmaxf(v, 0.f);
                C[(size_t)(row0 + r)*N + col] = __float2bfloat16(v);
            }
        }
    }
}

// ---------------------------------------------------------------------------
// Final layer 256->7 (bf16 input) fused with (BHW,7)->(B,7,H,W) transpose.
// ---------------------------------------------------------------------------
__global__ __launch_bounds__(256) void final_kernel(
    const __hip_bfloat16* __restrict__ h, const float* __restrict__ w,
    const float* __restrict__ bias, float* __restrict__ out)
{
    __shared__ float wsm[HID_*NC_];
    __shared__ float bs[NC_];
    const int tid = threadIdx.x;
    for (int i = tid; i < HID_*NC_; i += 256) wsm[i] = w[i];
    if (tid < NC_) bs[tid] = bias[tid];
    __syncthreads();

    const int row = blockIdx.x*256 + tid;   // 0..65535
    const uint4* hp = (const uint4*)(h + (size_t)row*HID_);
    float acc[NC_];
    #pragma unroll
    for (int j = 0; j < NC_; j++) acc[j] = bs[j];

    for (int k8 = 0; k8 < HID_/8; k8++){
        uint4 u = hp[k8];
        float v[8];
        v[0] = __uint_as_float(u.x << 16); v[1] = __uint_as_float(u.x & 0xffff0000u);
        v[2] = __uint_as_float(u.y << 16); v[3] = __uint_as_float(u.y & 0xffff0000u);
        v[4] = __uint_as_float(u.z << 16); v[5] = __uint_as_float(u.z & 0xffff0000u);
        v[6] = __uint_as_float(u.w << 16); v[7] = __uint_as_float(u.w & 0xffff0000u);
        const int k = k8*8;
        #pragma unroll
        for (int e = 0; e < 8; e++){
            #pragma unroll
            for (int j = 0; j < NC_; j++)
                acc[j] = fmaf(v[e], wsm[(k+e)*NC_ + j], acc[j]);
        }
    }
    const int b = row >> 12, hw = row & 4095;
    #pragma unroll
    for (int j = 0; j < NC_; j++)
        out[(size_t)(b*NC_ + j)*HW_ + hw] = acc[j];
}

// ---------------------------------------------------------------------------
// Workspace plan (peak 159,383,552 bytes, same as round 2):
//   yseq  bf16 [50][256][4096]  @ 0           (104,857,600 B)  ODE w, DFT r
//   fbuf  bf16 [65536][416]     @ 104,857,600 ( 54,525,952 B)  DFT w, GEMM1 r
//     conv temps aliased at fbuf+0..20MB (dead before DFT writes)
//   h1 bf16 [M][256] @ 0            (33,554,432)  GEMM1 out (yseq dead)
//   h2 bf16          @ 33,554,432                GEMM2 out
//   h3 bf16          @ 67,108,864                GEMM3 out
//   Wt1/2/3 bf16     @ 100,663,296+  (475,136 B, inside dead yseq tail)
// ---------------------------------------------------------------------------
extern "C" void kernel_launch(void* const* d_in, const int* in_sizes, int n_in,
                              void* d_out, int out_size, void* d_ws, size_t ws_size,
                              hipStream_t stream)
{
    const float* x     = (const float*)d_in[0];
    const float* om_w1 = (const float*)d_in[1];  const float* om_b1 = (const float*)d_in[2];
    const float* om_w2 = (const float*)d_in[3];  const float* om_b2 = (const float*)d_in[4];
    const float* om_w3 = (const float*)d_in[5];  const float* om_b3 = (const float*)d_in[6];
    const float* al_w1 = (const float*)d_in[7];  const float* al_b1 = (const float*)d_in[8];
    const float* al_w2 = (const float*)d_in[9];  const float* al_b2 = (const float*)d_in[10];
    const float* al_w3 = (const float*)d_in[11]; const float* al_b3 = (const float*)d_in[12];
    const float* hy_w1 = (const float*)d_in[13]; const float* hy_b1 = (const float*)d_in[14];
    const float* hy_w2 = (const float*)d_in[15]; const float* hy_b2 = (const float*)d_in[16];
    const float* hy_w3 = (const float*)d_in[17]; const float* hy_b3 = (const float*)d_in[18];
    const float* hy_w4 = (const float*)d_in[19]; const float* hy_b4 = (const float*)d_in[20];
    const float* wy    = (const float*)d_in[21];
    const float* ro_w1 = (const float*)d_in[22]; const float* ro_b1 = (const float*)d_in[23];
    const float* ro_w2 = (const float*)d_in[24]; const float* ro_b2 = (const float*)d_in[25];
    const float* ro_w3 = (const float*)d_in[26]; const float* ro_b3 = (const float*)d_in[27];
    const float* ro_w4 = (const float*)d_in[28]; const float* ro_b4 = (const float*)d_in[29];
    float* out = (float*)d_out;

    char* wsb = (char*)d_ws;
    const size_t YSEQ_BYTES = (size_t)T_ * BCHW_ * 2;          // 104,857,600
    __hip_bfloat16* yseq = (__hip_bfloat16*)wsb;
    __hip_bfloat16* fbuf = (__hip_bfloat16*)(wsb + YSEQ_BYTES);

    const size_t MB4 = (size_t)BCHW_ * 4;                      // 4 MiB
    float* tmp1  = (float*)(wsb + YSEQ_BYTES + 0*MB4);
    float* tmp2  = (float*)(wsb + YSEQ_BYTES + 1*MB4);
    float* omega = (float*)(wsb + YSEQ_BYTES + 2*MB4);
    float* alpha = (float*)(wsb + YSEQ_BYTES + 3*MB4);
    float* hy0   = (float*)(wsb + YSEQ_BYTES + 4*MB4);

    const size_t HB = (size_t)M_ * HID_ * 2;                   // 33,554,432
    __hip_bfloat16* h1 = (__hip_bfloat16*)(wsb + 0);
    __hip_bfloat16* h2 = (__hip_bfloat16*)(wsb + HB);
    __hip_bfloat16* h3 = (__hip_bfloat16*)(wsb + 2*HB);
    __hip_bfloat16* wt1 = (__hip_bfloat16*)(wsb + 3*HB);               // 212,992 B
    __hip_bfloat16* wt2 = (__hip_bfloat16*)(wsb + 3*HB + 212992);      // 131,072 B
    __hip_bfloat16* wt3 = (__hip_bfloat16*)(wsb + 3*HB + 344064);      // 131,072 B

    dim3 blk(256);
    // encoders
    conv3x3_kernel<1,0> <<<256, blk, 0, stream>>>(x,    om_w1, om_b1, tmp1);
    conv3x3_kernel<16,0><<<256, blk, 0, stream>>>(tmp1, om_w2, om_b2, tmp2);
    conv3x3_kernel<16,0><<<256, blk, 0, stream>>>(tmp2, om_w3, om_b3, omega);
    conv3x3_kernel<1,0> <<<256, blk, 0, stream>>>(x,    al_w1, al_b1, tmp1);
    conv3x3_kernel<16,0><<<256, blk, 0, stream>>>(tmp1, al_w2, al_b2, tmp2);
    conv3x3_kernel<16,0><<<256, blk, 0, stream>>>(tmp2, al_w3, al_b3, alpha);
    conv3x3_kernel<1,0> <<<256, blk, 0, stream>>>(x,    hy_w1, hy_b1, tmp1);
    conv3x3_kernel<16,0><<<256, blk, 0, stream>>>(tmp1, hy_w2, hy_b2, tmp2);
    conv3x3_kernel<16,0><<<256, blk, 0, stream>>>(tmp2, hy_w3, hy_b3, tmp1);
    conv3x3_kernel<16,1><<<256, blk, 0, stream>>>(tmp1, hy_w4, hy_b4, hy0);
    // 50-step ODE
    ode_kernel<<<256, blk, 0, stream>>>(omega, alpha, hy0, wy, yseq);
    // rfft magnitude -> row-major bf16 features
    dft_kernel<<<4096, blk, 0, stream>>>(yseq, fbuf);
    // weight transposes (yseq dead now; wt buffers live in its tail)
    prep_wt_kernel<<<256, blk, 0, stream>>>(ro_w1, wt1, F_,   HID_);
    prep_wt_kernel<<<256, blk, 0, stream>>>(ro_w2, wt2, HID_, HID_);
    prep_wt_kernel<<<256, blk, 0, stream>>>(ro_w3, wt3, HID_, HID_);
    // readout MLP (MFMA)
    gemm_mfma_kernel<<<dim3(512,2), blk, 0, stream>>>(fbuf, wt1, ro_b1, h1, M_, HID_, F_);
    gemm_mfma_kernel<<<dim3(512,2), blk, 0, stream>>>(h1,   wt2, ro_b2, h2, M_, HID_, HID_);
    gemm_mfma_kernel<<<dim3(512,2), blk, 0, stream>>>(h2,   wt3, ro_b3, h3, M_, HID_, HID_);
    final_kernel<<<256, blk, 0, stream>>>(h3, ro_w4, ro_b4, out);
}

// Round 4
// 472.332 us; speedup vs baseline: 2.2836x; 1.7445x over previous
//
#include <hip/hip_runtime.h>
#include <hip/hip_bf16.h>
#include <math.h>

#define B_   16
#define C_   16
#define S_   64
#define HW_  4096
#define T_   50
#define K_   26
#define F_   416   // C_*K_
#define HID_ 256
#define NC_  7
#define DT_  0.5f
#define BCHW_ (B_*C_*HW_)
#define M_   (B_*HW_)   // 65536 rows into the MLP

typedef short bf16x8 __attribute__((ext_vector_type(8)));
typedef float f32x4  __attribute__((ext_vector_type(4)));

__device__ __forceinline__ void gld_lds16(const void* g, void* l){
    __builtin_amdgcn_global_load_lds(
        (const __attribute__((address_space(1))) void*)g,
        (__attribute__((address_space(3))) void*)l, 16, 0, 0);
}

__device__ __forceinline__ float fast_tanh(float x){
    float ax = fabsf(x);
    float e  = __expf(2.f*ax);
    float r  = 1.f - 2.f/(e + 1.f);
    return copysignf(r, x);
}

// ---------------------------------------------------------------------------
// Fused multi-chain 3x3 conv, zero 'SAME' padding.
// Block = (slice of 16 rows, batch, chain); 1024 threads; each thread computes
// 1 output pixel for ALL 16 output channels (stencil staged once in LDS,
// weights are lane-uniform -> scalar loads).
// ---------------------------------------------------------------------------
template<int CIN, int ACT>
__global__ __launch_bounds__(1024) void convf_kernel(
    const float* __restrict__ in0, const float* __restrict__ in1, const float* __restrict__ in2,
    const float* __restrict__ w0,  const float* __restrict__ w1,  const float* __restrict__ w2,
    const float* __restrict__ b0,  const float* __restrict__ b1,  const float* __restrict__ b2,
    float* __restrict__ o0, float* __restrict__ o1, float* __restrict__ o2)
{
    __shared__ float slab[CIN][18][66];
    const int slice = blockIdx.x;        // 0..3 -> rows 16*slice..16*slice+15
    const int b     = blockIdx.y;
    const int ch    = blockIdx.z;
    const float* in = (ch == 0) ? in0 : (ch == 1) ? in1 : in2;
    const float* w  = (ch == 0) ? w0  : (ch == 1) ? w1  : w2;
    const float* bb = (ch == 0) ? b0  : (ch == 1) ? b1  : b2;
    float* out      = (ch == 0) ? o0  : (ch == 1) ? o1  : o2;

    const int tid = threadIdx.x;
    const int y0  = slice * 16;

    // stage rows y0-1..y0+16 (18), cols -1..64 (66) of all CIN planes, 0-padded
    for (int idx = tid; idx < CIN*18*66; idx += 1024){
        int ci  = idx / (18*66);
        int rem = idx % (18*66);
        int rr  = rem / 66;
        int cc  = rem % 66;
        int gy = y0 - 1 + rr;
        int gx = cc - 1;
        float v = 0.f;
        if ((unsigned)gy < 64u && (unsigned)gx < 64u)
            v = in[(size_t)(b*CIN + ci)*HW_ + gy*64 + gx];
        slab[ci][rr][cc] = v;
    }
    __syncthreads();

    const int x  = tid & 63;
    const int ry = tid >> 6;            // 0..15

    float acc[16];
    #pragma unroll
    for (int co = 0; co < 16; co++) acc[co] = bb[co];

    for (int ci = 0; ci < CIN; ci++){
        float p[3][3];
        #pragma unroll
        for (int dy = 0; dy < 3; dy++)
            #pragma unroll
            for (int dx = 0; dx < 3; dx++)
                p[dy][dx] = slab[ci][ry + dy][x + dx];
        #pragma unroll
        for (int co = 0; co < 16; co++){
            const float* wp = w + (size_t)(co*CIN + ci)*9;  // lane-uniform
            float s = acc[co];
            #pragma unroll
            for (int dy = 0; dy < 3; dy++)
                #pragma unroll
                for (int dx = 0; dx < 3; dx++)
                    s = fmaf(wp[dy*3 + dx], p[dy][dx], s);
            acc[co] = s;
        }
    }
    #pragma unroll
    for (int co = 0; co < 16; co++){
        float v = acc[co];
        v = ACT ? fast_tanh(v) : fmaxf(v, 0.f);
        out[(size_t)(b*16 + co)*HW_ + (y0 + ry)*64 + x] = v;
    }
}

// ---------------------------------------------------------------------------
// 50-step coRNN ODE. One block per (b,c) field, 1024 threads; each thread
// owns a 4x1 column segment in registers; field in LDS column-major with
// stride 65 (bank-conflict-free). 14 LDS reads/thread/step, 1 barrier/step.
// ---------------------------------------------------------------------------
__global__ __launch_bounds__(1024) void ode_kernel(
    const float* __restrict__ omega, const float* __restrict__ alpha,
    const float* __restrict__ hy0,   const float* __restrict__ wy,
    __hip_bfloat16* __restrict__ yseq)
{
    __shared__ float buf[2][64*65];
    const int blk = blockIdx.x;            // b*16 + c
    const int c   = blk & 15;
    const int tid = threadIdx.x;
    const int x   = tid & 63;
    const int sy  = (tid >> 6) << 2;       // 0,4,...,60
    const size_t off = (size_t)blk * HW_;

    float om[4], al[4], hz[4], hy[4];
    #pragma unroll
    for (int i = 0; i < 4; i++){
        size_t g = off + (size_t)(sy + i)*64 + x;
        om[i] = omega[g];
        al[i] = alpha[g];
        hz[i] = 0.f;
        hy[i] = hy0[g];
        buf[0][x*65 + sy + i] = hy[i];
    }
    float wv[9];
    const float* wp = wy + (size_t)(c*C_ + c)*9;
    #pragma unroll
    for (int j = 0; j < 9; j++) wv[j] = wp[j];
    __syncthreads();

    const int xl = ((x + 63) & 63) * 65;
    const int xr = ((x + 1)  & 63) * 65;
    const int xo = x * 65;
    const int ylo = (sy + 63) & 63;
    const int yhi = (sy + 4)  & 63;

    int cur = 0;
    for (int t = 0; t < T_; t++){
        const float* hp = buf[cur];
        float* hn = buf[cur ^ 1];
        float l[6], r[6];
        l[0] = hp[xl + ylo];  r[0] = hp[xr + ylo];
        #pragma unroll
        for (int i = 0; i < 4; i++){ l[i+1] = hp[xl + sy + i]; r[i+1] = hp[xr + sy + i]; }
        l[5] = hp[xl + yhi];  r[5] = hp[xr + yhi];
        float tN = hp[xo + ylo];
        float tS = hp[xo + yhi];

        __hip_bfloat16* yout = yseq + (size_t)t*BCHW_ + off;
        float ny[4];
        #pragma unroll
        for (int i = 0; i < 4; i++){
            float up = (i == 0) ? tN : hy[i-1];
            float dn = (i == 3) ? tS : hy[i+1];
            float s = wv[0]*l[i]   + wv[1]*up    + wv[2]*r[i]
                    + wv[3]*l[i+1] + wv[4]*hy[i] + wv[5]*r[i+1]
                    + wv[6]*l[i+2] + wv[7]*dn    + wv[8]*r[i+2];
            float sf = fast_tanh(s);
            float nz = hz[i] + DT_*(sf - om[i]*hy[i] - al[i]*hz[i]);
            float v  = hy[i] + DT_*nz;
            hz[i] = nz;
            ny[i] = v;
        }
        #pragma unroll
        for (int i = 0; i < 4; i++){
            hy[i] = ny[i];
            hn[xo + sy + i] = ny[i];
            yout[(sy + i)*64 + x] = __float2bfloat16(ny[i]);
        }
        __syncthreads();
        cur ^= 1;
    }
}

// ---------------------------------------------------------------------------
// rfft magnitude via Goertzel. One thread per (b,c,hw) row.
// Writes row-major feature matrix: f[(b*HW+hw)*416 + c*26 + k] (bf16).
// ---------------------------------------------------------------------------
__global__ __launch_bounds__(256) void dft_kernel(
    const __hip_bfloat16* __restrict__ yseq, __hip_bfloat16* __restrict__ f)
{
    __shared__ float ctab[K_];
    const int tid = threadIdx.x;
    if (tid < K_) ctab[tid] = cosf(6.283185307179586f * (float)tid / (float)T_);
    __syncthreads();

    const int blk = blockIdx.x;            // 4096 blocks
    const int bc  = blk >> 4;              // 0..255
    const int hw  = ((blk & 15) << 8) | tid;
    const int b = bc >> 4, c = bc & 15;

    float y[T_];
    const __hip_bfloat16* src = yseq + (size_t)bc*HW_ + hw;
    #pragma unroll
    for (int t = 0; t < T_; t++) y[t] = __bfloat162float(src[(size_t)t * BCHW_]);

    __hip_bfloat16* dst = f + (size_t)(b*HW_ + hw)*F_ + c*K_;
    for (int k = 0; k < K_; k++){
        float c1 = ctab[k];
        float tc = 2.f*c1;
        float s1 = 0.f, s2 = 0.f;
        #pragma unroll
        for (int t = 0; t < T_; t++){
            float s0 = fmaf(tc, s1, y[t] - s2);
            s2 = s1; s1 = s0;
        }
        float p = fmaf(s1, s1, fmaf(s2, s2, -tc*s1*s2));
        dst[k] = __float2bfloat16(sqrtf(fmaxf(p, 0.f)));
    }
}

// ---------------------------------------------------------------------------
// Weight prep: w[K][N] fp32 -> wt[N][K] bf16
// ---------------------------------------------------------------------------
__global__ __launch_bounds__(256) void prep_wt_kernel(
    const float* __restrict__ w, __hip_bfloat16* __restrict__ wt, int Kd, int N)
{
    const int n = blockIdx.x;
    for (int k = threadIdx.x; k < Kd; k += 256)
        wt[(size_t)n*Kd + k] = __float2bfloat16(w[(size_t)k*N + n]);
}

// ---------------------------------------------------------------------------
// MFMA GEMM: C = relu(A @ W + bias), bf16 in / fp32 acc / bf16 out.
// A [M][K] bf16, Wt [N][K] bf16, C [M][N] bf16. 128x128 tile, BK=32,
// 4 waves x (64x64), m97-style global_load_lds staging.
// ---------------------------------------------------------------------------
__global__ __launch_bounds__(256) void gemm_mfma_kernel(
    const __hip_bfloat16* __restrict__ A, const __hip_bfloat16* __restrict__ Wt,
    const float* __restrict__ bias, __hip_bfloat16* __restrict__ C,
    int M, int N, int Kd)
{
    __shared__ short As[128*32];
    __shared__ short Bs[128*32];
    const int tid  = threadIdx.x;
    const int lane = tid & 63;
    const int wave = tid >> 6;
    const int wm = (wave & 1) * 64;
    const int wn = (wave >> 1) * 64;
    const int m0 = blockIdx.x * 128;
    const int n0 = blockIdx.y * 128;

    f32x4 acc[4][4];
    #pragma unroll
    for (int i = 0; i < 4; i++)
        #pragma unroll
        for (int j = 0; j < 4; j++)
            acc[i][j] = (f32x4){0.f, 0.f, 0.f, 0.f};

    const int rloc = tid >> 2;
    const int kc   = (tid & 3) * 8;
    const char* Ag = (const char*)(A  + (size_t)(m0 + rloc)*Kd + kc);
    const char* Bg = (const char*)(Wt + (size_t)(n0 + rloc)*Kd + kc);
    const size_t rstride = (size_t)64 * Kd * 2;
    char* AsB = (char*)As + tid*16;
    char* BsB = (char*)Bs + tid*16;

    const int fa = (wm + (lane & 15)) * 32 + (lane >> 4) * 8;
    const int fb = (wn + (lane & 15)) * 32 + (lane >> 4) * 8;

    for (int k0 = 0; k0 < Kd; k0 += 32){
        const char* ag = Ag + (size_t)k0 * 2;
        const char* bg = Bg + (size_t)k0 * 2;
        gld_lds16(ag,           AsB);
        gld_lds16(ag + rstride, AsB + 4096);
        gld_lds16(bg,           BsB);
        gld_lds16(bg + rstride, BsB + 4096);
        __syncthreads();

        bf16x8 af[4], bfv[4];
        #pragma unroll
        for (int i = 0; i < 4; i++){
            af[i]  = *(const bf16x8*)&As[fa + i*16*32];
            bfv[i] = *(const bf16x8*)&Bs[fb + i*16*32];
        }
        #pragma unroll
        for (int i = 0; i < 4; i++)
            #pragma unroll
            for (int j = 0; j < 4; j++)
                acc[i][j] = __builtin_amdgcn_mfma_f32_16x16x32_bf16(
                                af[i], bfv[j], acc[i][j], 0, 0, 0);
        __syncthreads();
    }

    const int colb = n0 + wn + (lane & 15);
    const int rowb = m0 + wm + ((lane >> 4) << 2);
    #pragma unroll
    for (int j = 0; j < 4; j++){
        const int col = colb + j*16;
        const float bv = bias[col];
        #pragma unroll
        for (int i = 0; i < 4; i++){
            const int row0 = rowb + i*16;
            #pragma unroll
            for (int r = 0; r < 4; r++){
                float v = acc[i][j][r] + bv;
                v = fmaxf(v, 0.f);
                C[(size_t)(row0 + r)*N + col] = __float2bfloat16(v);
            }
        }
    }
}

// ---------------------------------------------------------------------------
// Final layer 256->7 (bf16 input) fused with (BHW,7)->(B,7,H,W) transpose.
// ---------------------------------------------------------------------------
__global__ __launch_bounds__(256) void final_kernel(
    const __hip_bfloat16* __restrict__ h, const float* __restrict__ w,
    const float* __restrict__ bias, float* __restrict__ out)
{
    __shared__ float wsm[HID_*NC_];
    __shared__ float bs[NC_];
    const int tid = threadIdx.x;
    for (int i = tid; i < HID_*NC_; i += 256) wsm[i] = w[i];
    if (tid < NC_) bs[tid] = bias[tid];
    __syncthreads();

    const int row = blockIdx.x*256 + tid;
    const uint4* hp = (const uint4*)(h + (size_t)row*HID_);
    float acc[NC_];
    #pragma unroll
    for (int j = 0; j < NC_; j++) acc[j] = bs[j];

    for (int k8 = 0; k8 < HID_/8; k8++){
        uint4 u = hp[k8];
        float v[8];
        v[0] = __uint_as_float(u.x << 16); v[1] = __uint_as_float(u.x & 0xffff0000u);
        v[2] = __uint_as_float(u.y << 16); v[3] = __uint_as_float(u.y & 0xffff0000u);
        v[4] = __uint_as_float(u.z << 16); v[5] = __uint_as_float(u.z & 0xffff0000u);
        v[6] = __uint_as_float(u.w << 16); v[7] = __uint_as_float(u.w & 0xffff0000u);
        const int k = k8*8;
        #pragma unroll
        for (int e = 0; e < 8; e++){
            #pragma unroll
            for (int j = 0; j < NC_; j++)
                acc[j] = fmaf(v[e], wsm[(k+e)*NC_ + j], acc[j]);
        }
    }
    const int b = row >> 12, hw = row & 4095;
    #pragma unroll
    for (int j = 0; j < NC_; j++)
        out[(size_t)(b*NC_ + j)*HW_ + hw] = acc[j];
}

// ---------------------------------------------------------------------------
// Workspace (peak 159,383,552 B):
//   yseq bf16 [50][256][4096] @ 0 (104,857,600)
//   fbuf bf16 [65536][416] @ 104,857,600 (54,525,952)
//     conv temps aliased in fbuf region (dead before DFT): 10 x 4 MiB
//   h1/h2/h3 bf16 + wt1/2/3 in dead-yseq region after DFT.
// ---------------------------------------------------------------------------
extern "C" void kernel_launch(void* const* d_in, const int* in_sizes, int n_in,
                              void* d_out, int out_size, void* d_ws, size_t ws_size,
                              hipStream_t stream)
{
    const float* x     = (const float*)d_in[0];
    const float* om_w1 = (const float*)d_in[1];  const float* om_b1 = (const float*)d_in[2];
    const float* om_w2 = (const float*)d_in[3];  const float* om_b2 = (const float*)d_in[4];
    const float* om_w3 = (const float*)d_in[5];  const float* om_b3 = (const float*)d_in[6];
    const float* al_w1 = (const float*)d_in[7];  const float* al_b1 = (const float*)d_in[8];
    const float* al_w2 = (const float*)d_in[9];  const float* al_b2 = (const float*)d_in[10];
    const float* al_w3 = (const float*)d_in[11]; const float* al_b3 = (const float*)d_in[12];
    const float* hy_w1 = (const float*)d_in[13]; const float* hy_b1 = (const float*)d_in[14];
    const float* hy_w2 = (const float*)d_in[15]; const float* hy_b2 = (const float*)d_in[16];
    const float* hy_w3 = (const float*)d_in[17]; const float* hy_b3 = (const float*)d_in[18];
    const float* hy_w4 = (const float*)d_in[19]; const float* hy_b4 = (const float*)d_in[20];
    const float* wy    = (const float*)d_in[21];
    const float* ro_w1 = (const float*)d_in[22]; const float* ro_b1 = (const float*)d_in[23];
    const float* ro_w2 = (const float*)d_in[24]; const float* ro_b2 = (const float*)d_in[25];
    const float* ro_w3 = (const float*)d_in[26]; const float* ro_b3 = (const float*)d_in[27];
    const float* ro_w4 = (const float*)d_in[28]; const float* ro_b4 = (const float*)d_in[29];
    float* out = (float*)d_out;

    char* wsb = (char*)d_ws;
    const size_t YSEQ_BYTES = (size_t)T_ * BCHW_ * 2;          // 104,857,600
    __hip_bfloat16* yseq = (__hip_bfloat16*)wsb;
    __hip_bfloat16* fbuf = (__hip_bfloat16*)(wsb + YSEQ_BYTES);

    const size_t MB4 = (size_t)BCHW_ * 4;                      // 4 MiB
    float* om_t1 = (float*)(wsb + YSEQ_BYTES + 0*MB4);
    float* al_t1 = (float*)(wsb + YSEQ_BYTES + 1*MB4);
    float* hy_t1 = (float*)(wsb + YSEQ_BYTES + 2*MB4);
    float* om_t2 = (float*)(wsb + YSEQ_BYTES + 3*MB4);
    float* al_t2 = (float*)(wsb + YSEQ_BYTES + 4*MB4);
    float* hy_t2 = (float*)(wsb + YSEQ_BYTES + 5*MB4);
    float* omega = (float*)(wsb + YSEQ_BYTES + 6*MB4);
    float* alpha = (float*)(wsb + YSEQ_BYTES + 7*MB4);
    float* hy_t3 = (float*)(wsb + YSEQ_BYTES + 8*MB4);
    float* hy0   = (float*)(wsb + YSEQ_BYTES + 9*MB4);

    const size_t HB = (size_t)M_ * HID_ * 2;                   // 33,554,432
    __hip_bfloat16* h1 = (__hip_bfloat16*)(wsb + 0);
    __hip_bfloat16* h2 = (__hip_bfloat16*)(wsb + HB);
    __hip_bfloat16* h3 = (__hip_bfloat16*)(wsb + 2*HB);
    __hip_bfloat16* wt1 = (__hip_bfloat16*)(wsb + 3*HB);
    __hip_bfloat16* wt2 = (__hip_bfloat16*)(wsb + 3*HB + 212992);
    __hip_bfloat16* wt3 = (__hip_bfloat16*)(wsb + 3*HB + 344064);

    // encoders: 3 chains fused per layer
    convf_kernel<1,0><<<dim3(4,B_,3), 1024, 0, stream>>>(
        x, x, x, om_w1, al_w1, hy_w1, om_b1, al_b1, hy_b1, om_t1, al_t1, hy_t1);
    convf_kernel<16,0><<<dim3(4,B_,3), 1024, 0, stream>>>(
        om_t1, al_t1, hy_t1, om_w2, al_w2, hy_w2, om_b2, al_b2, hy_b2, om_t2, al_t2, hy_t2);
    convf_kernel<16,0><<<dim3(4,B_,3), 1024, 0, stream>>>(
        om_t2, al_t2, hy_t2, om_w3, al_w3, hy_w3, om_b3, al_b3, hy_b3, omega, alpha, hy_t3);
    convf_kernel<16,1><<<dim3(4,B_,1), 1024, 0, stream>>>(
        hy_t3, hy_t3, hy_t3, hy_w4, hy_w4, hy_w4, hy_b4, hy_b4, hy_b4, hy0, hy0, hy0);
    // 50-step ODE
    ode_kernel<<<256, 1024, 0, stream>>>(omega, alpha, hy0, wy, yseq);
    // rfft magnitude -> row-major bf16 features
    dft_kernel<<<4096, 256, 0, stream>>>(yseq, fbuf);
    // weight transposes (yseq dead; wt in its tail)
    prep_wt_kernel<<<256, 256, 0, stream>>>(ro_w1, wt1, F_,   HID_);
    prep_wt_kernel<<<256, 256, 0, stream>>>(ro_w2, wt2, HID_, HID_);
    prep_wt_kernel<<<256, 256, 0, stream>>>(ro_w3, wt3, HID_, HID_);
    // readout MLP (MFMA)
    gemm_mfma_kernel<<<dim3(512,2), 256, 0, stream>>>(fbuf, wt1, ro_b1, h1, M_, HID_, F_);
    gemm_mfma_kernel<<<dim3(512,2), 256, 0, stream>>>(h1,   wt2, ro_b2, h2, M_, HID_, HID_);
    gemm_mfma_kernel<<<dim3(512,2), 256, 0, stream>>>(h2,   wt3, ro_b3, h3, M_, HID_, HID_);
    final_kernel<<<256, 256, 0, stream>>>(h3, ro_w4, ro_b4, out);
}